// Round 1
// baseline (246.910 us; speedup 1.0000x reference)
//
#include <hip/hip_runtime.h>

namespace {

constexpr int F    = 128;
constexpr int L    = 4096;
constexpr int Bsz  = 32;
constexpr int ROWS = 32;   // output rows per block
constexpr int XS   = 132;  // padded LDS row stride (floats)

// Fold the 8 heads into averaged, transposed weights:
// WT[k][o], k in [0,256): k<128 -> mean_h W_src[(h*128+o)*128+k]
//                         k>=128 -> mean_h W_res[(h*128+o)*128+(k-128)]
// bbar[o] = mean_h bias[h*128+o]
__global__ void prep_weights(const float* __restrict__ Wsrc,
                             const float* __restrict__ Wres,
                             const float* __restrict__ bias,
                             float* __restrict__ WT,
                             float* __restrict__ bbar)
{
    int idx = blockIdx.x * 256 + threadIdx.x;
    if (idx < 2 * F * F) {
        int k = idx >> 7;
        int o = idx & (F - 1);
        const float* W = (k < F) ? Wsrc : Wres;
        int e = k & (F - 1);
        float s = 0.f;
#pragma unroll
        for (int h = 0; h < 8; ++h)
            s += W[(h * F + o) * F + e];
        WT[k * F + o] = s * 0.125f;
    }
    if (idx < F) {
        float s = 0.f;
#pragma unroll
        for (int h = 0; h < 8; ++h) s += bias[h * F + idx];
        bbar[idx] = s * 0.125f;
    }
}

__device__ inline void fma8(float (&acc)[8], float x, const float4& wa, const float4& wb) {
    acc[0] += x * wa.x; acc[1] += x * wa.y; acc[2] += x * wa.z; acc[3] += x * wa.w;
    acc[4] += x * wb.x; acc[5] += x * wb.y; acc[6] += x * wb.z; acc[7] += x * wb.w;
}

__global__ __launch_bounds__(256)
void gat_main(const float* __restrict__ loc,
              const float* __restrict__ WT,
              const float* __restrict__ bbar,
              float* __restrict__ out)
{
    __shared__ float xs[(ROWS + 1) * XS];
    const int b  = blockIdx.y;
    const int p0 = blockIdx.x * ROWS;
    const float* locb = loc + (size_t)b * L * F;
    const int t = threadIdx.x;

    // stage loc rows p0-1 .. p0+ROWS-1 into LDS rows 0..ROWS
    for (int i = t; i < (ROWS + 1) * F; i += 256) {
        int r = i >> 7;
        int c = i & (F - 1);
        int p = p0 - 1 + r;
        xs[r * XS + c] = (p >= 0) ? locb[(size_t)p * F + c] : 0.f;
    }
    __syncthreads();

    // thread micro-tile: 2 rows x 8 cols
    const int oc = (t & 15) * 8;   // output col base
    const int rg = t >> 4;         // 0..15
    const int r0 = rg * 2;
    const int r1 = r0 + 1;

    float acc0[8], acc1[8];
#pragma unroll
    for (int j = 0; j < 8; ++j) { acc0[j] = 0.f; acc1[j] = 0.f; }

    const float4* w4 = reinterpret_cast<const float4*>(WT) + (oc >> 2);
    const float* x0p = xs + r0 * XS;  // prev-row inputs for output row p0+r0
    const float* x1p = xs + r1 * XS;

    // K-half 1: prev row x W_src-bar
#pragma unroll 8
    for (int k = 0; k < F; ++k) {
        float4 wa = w4[k * 32];
        float4 wb = w4[k * 32 + 1];
        float x0 = x0p[k];
        float x1 = x1p[k];
        fma8(acc0, x0, wa, wb);
        fma8(acc1, x1, wa, wb);
    }
    // K-half 2: current row x W_res-bar
#pragma unroll 8
    for (int k = 0; k < F; ++k) {
        float4 wa = w4[(F + k) * 32];
        float4 wb = w4[(F + k) * 32 + 1];
        float x0 = x0p[XS + k];
        float x1 = x1p[XS + k];
        fma8(acc0, x0, wa, wb);
        fma8(acc1, x1, wa, wb);
    }

    float bv[8];
#pragma unroll
    for (int j = 0; j < 8; ++j) bv[j] = bbar[oc + j];

    float* outb = out + (size_t)b * L * F;
    const int p_0 = p0 + r0;
    const int p_1 = p0 + r1;   // always >= 1

    float4 s0a, s0b;
    if (p_0 == 0) {
        // out[b,0,:] = loc[b,0,:]  (LDS row 1 holds loc[b,0])
        s0a = *reinterpret_cast<const float4*>(xs + XS + oc);
        s0b = *reinterpret_cast<const float4*>(xs + XS + oc + 4);
    } else {
        s0a = make_float4(acc0[0] + bv[0], acc0[1] + bv[1], acc0[2] + bv[2], acc0[3] + bv[3]);
        s0b = make_float4(acc0[4] + bv[4], acc0[5] + bv[5], acc0[6] + bv[6], acc0[7] + bv[7]);
    }
    *reinterpret_cast<float4*>(outb + (size_t)p_0 * F + oc)     = s0a;
    *reinterpret_cast<float4*>(outb + (size_t)p_0 * F + oc + 4) = s0b;

    float4 s1a = make_float4(acc1[0] + bv[0], acc1[1] + bv[1], acc1[2] + bv[2], acc1[3] + bv[3]);
    float4 s1b = make_float4(acc1[4] + bv[4], acc1[5] + bv[5], acc1[6] + bv[6], acc1[7] + bv[7]);
    *reinterpret_cast<float4*>(outb + (size_t)p_1 * F + oc)     = s1a;
    *reinterpret_cast<float4*>(outb + (size_t)p_1 * F + oc + 4) = s1b;
}

} // namespace

extern "C" void kernel_launch(void* const* d_in, const int* in_sizes, int n_in,
                              void* d_out, int out_size, void* d_ws, size_t ws_size,
                              hipStream_t stream) {
    const float* loc  = (const float*)d_in[0];
    const float* Wsrc = (const float*)d_in[1];
    // d_in[2] W_dst, d_in[3] attn_l, d_in[4] attn_r: cancel (alpha == 1), unused
    const float* Wres = (const float*)d_in[5];
    const float* bias = (const float*)d_in[6];

    float* WT   = (float*)d_ws;                 // 256*128 floats
    float* bbar = WT + 2 * F * F;               // 128 floats
    float* outp = (float*)d_out;

    prep_weights<<<128, 256, 0, stream>>>(Wsrc, Wres, bias, WT, bbar);

    dim3 grid(L / ROWS, Bsz);
    gat_main<<<grid, 256, 0, stream>>>(loc, WT, bbar, outp);
}

// Round 2
// 44.578 us; speedup vs baseline: 5.5389x; 5.5389x over previous
//
#include <hip/hip_runtime.h>

namespace {

constexpr int F   = 128;
constexpr int L   = 4096;
constexpr int Bsz = 32;
constexpr int TR  = 128;                  // output rows per block
constexpr int NT  = 8;                    // n-tiles of 16 (128 cols)
constexpr int LDS_A_BYTES = (TR + 1) * F * 2;   // 129 rows * 256 B = 33024
constexpr int LDS_B_BYTES = 2 * F * F * 2;      // 65536

using short8   = __attribute__((ext_vector_type(8))) short;
using ushort4v = __attribute__((ext_vector_type(4))) unsigned short;
using f32x4    = __attribute__((ext_vector_type(4))) float;

__device__ inline unsigned short f2bf(float x) {
    unsigned u = __builtin_bit_cast(unsigned, x);
    unsigned r = (u + 0x7fffu + ((u >> 16) & 1u)) >> 16;
    return (unsigned short)r;
}

// Fold 8 heads into averaged weights, emitted directly in MFMA B-fragment
// chunk order: flat bf16 index idx -> j = idx&7, chunk c = idx>>3,
// n = c&127, sg = c>>7 (s*4+g), k = sg*8+j.  Wbar[k][n]:
//   k<128: mean_h W_src[(h*128+n)*128+k]; k>=128: mean_h W_res[...][k-128]
__global__ void prep(const float* __restrict__ Wsrc,
                     const float* __restrict__ Wres,
                     const float* __restrict__ bias,
                     unsigned short* __restrict__ Wf,
                     float* __restrict__ bbar)
{
    int idx = blockIdx.x * 256 + threadIdx.x;
    if (idx < 2 * F * F) {
        int j  = idx & 7;
        int c  = idx >> 3;
        int n  = c & (F - 1);
        int sg = c >> 7;
        int k  = sg * 8 + j;
        int e  = k & (F - 1);
        const float* W = (k < F) ? Wsrc : Wres;
        float s = 0.f;
#pragma unroll
        for (int h = 0; h < 8; ++h) s += W[(h * F + n) * F + e];
        Wf[idx] = f2bf(s * 0.125f);
    }
    if (idx < F) {
        float s = 0.f;
#pragma unroll
        for (int h = 0; h < 8; ++h) s += bias[h * F + idx];
        bbar[idx] = s * 0.125f;
    }
}

__global__ __launch_bounds__(512)
void gat_mfma(const float* __restrict__ loc,
              const unsigned short* __restrict__ Wf,
              const float* __restrict__ bbar,
              float* __restrict__ out)
{
    extern __shared__ char smem[];
    unsigned short* As = (unsigned short*)smem;                  // 129 x 128 bf16, swizzled
    unsigned short* Bs = (unsigned short*)(smem + LDS_A_BYTES);  // fragment-ordered weights

    const int b  = blockIdx.y;
    const int p0 = blockIdx.x * TR;
    const int t  = threadIdx.x;
    const float* locb = loc + (size_t)b * L * F;

    // stage A: loc rows p0-1 .. p0+TR-1 -> LDS rows 0..TR (bf16, XOR-swizzled)
    for (int i = t; i < (TR + 1) * (F / 4); i += 512) {
        int r  = i >> 5;        // F/4 = 32 float4 per row
        int c4 = i & 31;
        int p  = p0 - 1 + r;
        float4 v = (p >= 0) ? *(const float4*)(locb + (size_t)p * F + c4 * 4)
                            : make_float4(0.f, 0.f, 0.f, 0.f);
        ushort4v h;
        h[0] = f2bf(v.x); h[1] = f2bf(v.y); h[2] = f2bf(v.z); h[3] = f2bf(v.w);
        int byteoff = r * 256 + ((c4 * 8) ^ ((r & 7) << 4));
        *(ushort4v*)((char*)As + byteoff) = h;
    }
    // stage B: 64 KB linear copy (chunks already fragment-ordered)
    {
        const float4* src = (const float4*)Wf;
        float4*       dst = (float4*)Bs;
        for (int i = t; i < LDS_B_BYTES / 16; i += 512) dst[i] = src[i];
    }
    __syncthreads();

    const int w    = t >> 6;          // wave 0..7 -> rows w*16..w*16+15
    const int lane = t & 63;
    const int g    = lane >> 4;       // k lane-group
    const int ml   = w * 16 + (lane & 15);   // LDS row of prev-loc for this A row

    // A fragments: 8 x ds_read_b128 (4 col-groups x {prev,cur} row)
    short8 aprev[4], acur[4];
#pragma unroll
    for (int s2 = 0; s2 < 4; ++s2) {
        int colb = s2 * 64 + g * 16;
        aprev[s2] = *(const short8*)((char*)As + ml * 256       + (colb ^ ((ml & 7) << 4)));
        acur[s2]  = *(const short8*)((char*)As + (ml + 1) * 256 + (colb ^ (((ml + 1) & 7) << 4)));
    }

    f32x4 acc[NT];
#pragma unroll
    for (int i = 0; i < NT; ++i) { acc[i][0] = 0.f; acc[i][1] = 0.f; acc[i][2] = 0.f; acc[i][3] = 0.f; }

#pragma unroll
    for (int s = 0; s < 8; ++s) {
        short8 a = (s < 4) ? aprev[s] : acur[s - 4];
        const unsigned short* brow = Bs + ((size_t)((s * 4 + g) * F + (lane & 15))) * 8;
#pragma unroll
        for (int tn = 0; tn < NT; ++tn) {
            short8 bf = *(const short8*)(brow + tn * 16 * 8);
            acc[tn] = __builtin_amdgcn_mfma_f32_16x16x32_bf16(a, bf, acc[tn], 0, 0, 0);
        }
    }

    // epilogue: D row = (lane>>4)*4 + reg, col = tn*16 + (lane&15)
    float* outb = out + (size_t)b * L * F;
    const int rowg = (lane >> 4) * 4;
#pragma unroll
    for (int tn = 0; tn < NT; ++tn) {
        int col = tn * 16 + (lane & 15);
        float bb = bbar[col];
#pragma unroll
        for (int r = 0; r < 4; ++r) {
            int p = p0 + w * 16 + rowg + r;
            float val = acc[tn][r] + bb;
            if (p == 0) val = locb[col];   // out[b,0,:] = loc[b,0,:] exact
            outb[(size_t)p * F + col] = val;
        }
    }
}

} // namespace

extern "C" void kernel_launch(void* const* d_in, const int* in_sizes, int n_in,
                              void* d_out, int out_size, void* d_ws, size_t ws_size,
                              hipStream_t stream) {
    const float* loc  = (const float*)d_in[0];
    const float* Wsrc = (const float*)d_in[1];
    // d_in[2] W_dst, d_in[3] attn_l, d_in[4] attn_r cancel (alpha == 1)
    const float* Wres = (const float*)d_in[5];
    const float* bias = (const float*)d_in[6];

    unsigned short* Wf   = (unsigned short*)d_ws;              // 32768 bf16 = 64 KB
    float*          bbar = (float*)((char*)d_ws + LDS_B_BYTES);
    float*          outp = (float*)d_out;

    prep<<<128, 256, 0, stream>>>(Wsrc, Wres, bias, Wf, bbar);

    size_t lds = LDS_A_BYTES + LDS_B_BYTES;   // 98560 B
    gat_mfma<<<dim3(L / TR, Bsz), 512, lds, stream>>>(loc, Wf, bbar, outp);
}

// Round 4
// 41.985 us; speedup vs baseline: 5.8810x; 1.0618x over previous
//
#include <hip/hip_runtime.h>

namespace {

constexpr int F   = 128;
constexpr int L   = 4096;
constexpr int Bsz = 32;
constexpr int TR  = 128;   // output rows per block
constexpr int NT  = 8;     // n-tiles of 16

using short8 = __attribute__((ext_vector_type(8))) short;
using f32x4  = __attribute__((ext_vector_type(4))) float;
using u32x4  = __attribute__((ext_vector_type(4))) unsigned int;

__device__ inline unsigned short f2bf(float x) {
    unsigned u = __builtin_bit_cast(unsigned, x);
    unsigned r = (u + 0x7fffu + ((u >> 16) & 1u)) >> 16;
    return (unsigned short)r;
}

__device__ inline unsigned pack2(float lo, float hi) {
    return (unsigned)f2bf(lo) | ((unsigned)f2bf(hi) << 16);
}

// Head-folded weights in MFMA-A-fragment order, arranged so one (s,tn)
// fragment read is 64 CONSECUTIVE 16B chunks (lane-linear -> conflict-free):
//   bf16 idx: j = idx&7, chunk c2 = idx>>3
//   l15 = c2&15, g = (c2>>4)&3, tn = (c2>>6)&7, s = c2>>9
//   n = tn*16 + l15,  k = (s*4+g)*8 + j
//   k<128: mean_h W_src[(h*128+n)*128+k]; k>=128: mean_h W_res[...][k-128]
__global__ void prep(const float* __restrict__ Wsrc,
                     const float* __restrict__ Wres,
                     const float* __restrict__ bias,
                     unsigned short* __restrict__ Wf,
                     float* __restrict__ bbar)
{
    int idx = blockIdx.x * 256 + threadIdx.x;
    if (idx < 2 * F * F) {
        int j   = idx & 7;
        int c2  = idx >> 3;
        int l15 = c2 & 15;
        int g   = (c2 >> 4) & 3;
        int tn  = (c2 >> 6) & 7;
        int s   = c2 >> 9;
        int n   = tn * 16 + l15;
        int k   = (s * 4 + g) * 8 + j;
        int e   = k & (F - 1);
        const float* W = (k < F) ? Wsrc : Wres;
        float sum = 0.f;
#pragma unroll
        for (int h = 0; h < 8; ++h) sum += W[(h * F + n) * F + e];
        Wf[idx] = f2bf(sum * 0.125f);
    }
    if (idx < F) {
        float s = 0.f;
#pragma unroll
        for (int h = 0; h < 8; ++h) s += bias[h * F + idx];
        bbar[idx] = s * 0.125f;
    }
}

__device__ inline short8 cvt8(float4 a, float4 b) {
    u32x4 u;
    u[0] = pack2(a.x, a.y);
    u[1] = pack2(a.z, a.w);
    u[2] = pack2(b.x, b.y);
    u[3] = pack2(b.z, b.w);
    return __builtin_bit_cast(short8, u);
}

__global__ __launch_bounds__(512, 4)
void gat_mfma(const float* __restrict__ loc,
              const unsigned short* __restrict__ Wf,
              const float* __restrict__ bbar,
              float* __restrict__ out)
{
    extern __shared__ char smem[];

    const int b    = blockIdx.y;
    const int p0   = blockIdx.x * TR;
    const int t    = threadIdx.x;
    const int lane = t & 63;
    const int w    = t >> 6;
    const int g    = lane >> 4;
    const int l15  = lane & 15;
    const float* locb = loc + (size_t)b * L * F;

    // ---- A: direct global->reg loads (issue first, in flight over B stage)
    const int prow  = p0 + w * 16 + l15;   // this lane's output row
    const int pprev = prow - 1;
    const float* apb = locb + (size_t)((pprev < 0) ? 0 : pprev) * F + g * 8;
    const float* acb = locb + (size_t)prow * F + g * 8;
    float4 ap[8], ac[8];
#pragma unroll
    for (int s = 0; s < 4; ++s) {
        ap[s * 2]     = *(const float4*)(apb + s * 32);
        ap[s * 2 + 1] = *(const float4*)(apb + s * 32 + 4);
        ac[s * 2]     = *(const float4*)(acb + s * 32);
        ac[s * 2 + 1] = *(const float4*)(acb + s * 32 + 4);
    }

    // ---- B: 64 KB global->LDS async, linear both sides
#pragma unroll
    for (int i = 0; i < 8; ++i) {
        int off = (i * 512 + t) * 16;
        __builtin_amdgcn_global_load_lds(
            (const __attribute__((address_space(1))) void*)((const char*)Wf + off),
            (__attribute__((address_space(3))) void*)(smem + (i * 512 + (t & ~63)) * 16),
            16, 0, 0);
    }

    if (pprev < 0) {
#pragma unroll
        for (int i = 0; i < 8; ++i) ap[i] = make_float4(0.f, 0.f, 0.f, 0.f);
    }

    // convert A to bf16 fragments while B stage completes
    short8 afr[8];
#pragma unroll
    for (int s = 0; s < 4; ++s) {
        afr[s]     = cvt8(ap[s * 2], ap[s * 2 + 1]);
        afr[s + 4] = cvt8(ac[s * 2], ac[s * 2 + 1]);
    }

    __syncthreads();

    f32x4 acc[NT];
#pragma unroll
    for (int i = 0; i < NT; ++i) { acc[i][0] = 0.f; acc[i][1] = 0.f; acc[i][2] = 0.f; acc[i][3] = 0.f; }

    const char* bs_base = (const char*)smem + lane * 16;
#pragma unroll
    for (int s = 0; s < 8; ++s) {
#pragma unroll
        for (int tn = 0; tn < NT; ++tn) {
            short8 wfrag = *(const short8*)(bs_base + ((s * 8 + tn) << 10));
            acc[tn] = __builtin_amdgcn_mfma_f32_16x16x32_bf16(wfrag, afr[s], acc[tn], 0, 0, 0);
        }
    }

    // ---- epilogue: lane holds cols (tn*16 + g*4 + r) of row `prow`
    float* outr = out + (size_t)b * L * F + (size_t)prow * F;
    const int colb = g * 4;
#pragma unroll
    for (int tn = 0; tn < NT; ++tn) {
        int col = tn * 16 + colb;
        float4 bb = *(const float4*)(bbar + col);
        float4 v = make_float4(acc[tn][0] + bb.x, acc[tn][1] + bb.y,
                               acc[tn][2] + bb.z, acc[tn][3] + bb.w);
        if (prow == 0) v = *(const float4*)(locb + col);   // out[b,0,:] = loc[b,0,:]
        *(float4*)(outr + col) = v;
    }
}

} // namespace

extern "C" void kernel_launch(void* const* d_in, const int* in_sizes, int n_in,
                              void* d_out, int out_size, void* d_ws, size_t ws_size,
                              hipStream_t stream) {
    const float* loc  = (const float*)d_in[0];
    const float* Wsrc = (const float*)d_in[1];
    // d_in[2] W_dst, d_in[3] attn_l, d_in[4] attn_r cancel (alpha == 1)
    const float* Wres = (const float*)d_in[5];
    const float* bias = (const float*)d_in[6];

    unsigned short* Wf   = (unsigned short*)d_ws;          // 32768 bf16 = 64 KB
    float*          bbar = (float*)((char*)d_ws + 2 * F * F * 2);
    float*          outp = (float*)d_out;

    prep<<<128, 256, 0, stream>>>(Wsrc, Wres, bias, Wf, bbar);

    gat_mfma<<<dim3(L / TR, Bsz), 512, 65536, stream>>>(loc, Wf, bbar, outp);
}